// Round 1
// 1119.391 us; speedup vs baseline: 1.2916x; 1.2916x over previous
//
#include <hip/hip_runtime.h>

typedef unsigned short ushort_t;
typedef __attribute__((ext_vector_type(8))) short short8;
typedef __attribute__((ext_vector_type(4))) float f32x4;

#define S_LEN 512
#define NB 16
#define NH 256
#define NV 10000

__device__ __forceinline__ unsigned short f2bf(float f){
  unsigned u = __float_as_uint(f);
  u += 0x7fffu + ((u >> 16) & 1u);          // RNE to bf16
  return (unsigned short)(u >> 16);
}

// ---------------- prep kernels ----------------

// x_emb gather + bf16 cvt, plus sequence-reversed copy for the backward RNN.
__global__ __launch_bounds__(256) void k_prep_xemb(const int* __restrict__ x,
    const float* __restrict__ emb, ushort_t* __restrict__ xe, ushort_t* __restrict__ xer){
  int g = blockIdx.x * 256 + threadIdx.x;      // 8192 rows * 32 chunks
  int m = g >> 5, c = (g & 31) << 3;
  int xm = x[m];
  const float* src = emb + (size_t)xm * NH + c;
  float4 a = *(const float4*)src, b = *(const float4*)(src + 4);
  union { ushort_t us[8]; uint4 v; } u;
  u.us[0]=f2bf(a.x); u.us[1]=f2bf(a.y); u.us[2]=f2bf(a.z); u.us[3]=f2bf(a.w);
  u.us[4]=f2bf(b.x); u.us[5]=f2bf(b.y); u.us[6]=f2bf(b.z); u.us[7]=f2bf(b.w);
  int s = m >> 4, bidx = m & 15;
  int mr = ((S_LEN - 1 - s) << 4) | bidx;
  *(uint4*)&xe [(size_t)m  * NH + c] = u.v;
  *(uint4*)&xer[(size_t)mr * NH + c] = u.v;
}

__global__ __launch_bounds__(256) void k_cvt(const float* __restrict__ src,
                                             ushort_t* __restrict__ dst, int n){
  int g = (blockIdx.x * 256 + threadIdx.x) * 8;
  if (g >= n) return;
  float4 a = *(const float4*)(src + g), b = *(const float4*)(src + g + 4);
  union { ushort_t us[8]; uint4 v; } u;
  u.us[0]=f2bf(a.x); u.us[1]=f2bf(a.y); u.us[2]=f2bf(a.z); u.us[3]=f2bf(a.w);
  u.us[4]=f2bf(b.x); u.us[5]=f2bf(b.y); u.us[6]=f2bf(b.z); u.us[7]=f2bf(b.w);
  *(uint4*)&dst[g] = u.v;
}

// fc_W[:, 0:256] -> bf16 [10112][256] (rows >= 10000 zero-padded)
__global__ __launch_bounds__(256) void k_prep_fcw(const float* __restrict__ fcW,
                                                  ushort_t* __restrict__ out){
  int g = blockIdx.x * 256 + threadIdx.x;      // 10112*32
  int v = g >> 5, c = (g & 31) << 3;
  union { ushort_t us[8]; uint4 q; } u;
  if (v < NV){
    const float* p = fcW + (size_t)v * 768 + c;
    float4 a = *(const float4*)p, b = *(const float4*)(p + 4);
    u.us[0]=f2bf(a.x); u.us[1]=f2bf(a.y); u.us[2]=f2bf(a.z); u.us[3]=f2bf(a.w);
    u.us[4]=f2bf(b.x); u.us[5]=f2bf(b.y); u.us[6]=f2bf(b.z); u.us[7]=f2bf(b.w);
  } else {
    u.q = make_uint4(0,0,0,0);
  }
  *(uint4*)&out[(size_t)v * NH + c] = u.q;
}

__global__ __launch_bounds__(256) void k_prep_tsT(const float* __restrict__ t,
    const float* __restrict__ s2, float* __restrict__ tT,
    float* __restrict__ sxT, float* __restrict__ syT){
  int g = blockIdx.x * 256 + threadIdx.x;   // 8192 = 512*16
  int j = g >> 4, b = g & 15;
  tT [b * S_LEN + j] = t[g];
  sxT[b * S_LEN + j] = s2[(size_t)g * 2];
  syT[b * S_LEN + j] = s2[(size_t)g * 2 + 1];
}

// pairwise decay weights: w bf16 [b][i][j] (0 for j>i), rsum = 1/sum_j w
__global__ __launch_bounds__(256) void k_prep_w(const float* __restrict__ tT,
    const float* __restrict__ sxT, const float* __restrict__ syT,
    ushort_t* __restrict__ wb, float* __restrict__ rsum){
  int i = blockIdx.x, b = blockIdx.y, tid = threadIdx.x;
  const float C1 = 7.272205216643040e-05f;   // 2*pi/86400
  const float C2 = -1.1574074074074074e-06f; // -0.1/86400
  float ti = tT[b*S_LEN+i], sxi = sxT[b*S_LEN+i], syi = syT[b*S_LEN+i];
  __shared__ float red[256];
  float psum = 0.f;
  #pragma unroll
  for (int u2 = 0; u2 < 2; u2++){
    int j = tid + u2 * 256;
    float w = 0.f;
    if (j <= i){
      float dt = ti - tT[b*S_LEN+j];
      float dx = sxi - sxT[b*S_LEN+j], dy = syi - syT[b*S_LEN+j];
      float ds = sqrtf(dx*dx + dy*dy);
      float a = (__cosf(dt * C1) + 1.f) * 0.5f * __expf(dt * C2);
      float bw = __expf(-100.f * ds);
      w = a * bw + 1e-10f;
    }
    psum += w;
    wb[((size_t)b * S_LEN + i) * S_LEN + j] = f2bf(w);
  }
  red[tid] = psum; __syncthreads();
  for (int st = 128; st > 0; st >>= 1){
    if (tid < st) red[tid] += red[tid + st];
    __syncthreads();
  }
  if (tid == 0) rsum[b * S_LEN + i] = 1.f / red[0];
}

// ulog[b][v] = p_u[b] . fc_W[v][512:768] + fc_b[v]
__global__ __launch_bounds__(256) void k_ulog(const int* __restrict__ au,
    const float* __restrict__ uemb, const float* __restrict__ fcW,
    const float* __restrict__ fcb, float* __restrict__ ulog){
  __shared__ float pl[16 * 256];
  int tid = threadIdx.x;
  for (int idx = tid; idx < 16 * 256; idx += 256){
    int b = idx >> 8, hc = idx & 255;
    pl[idx] = uemb[(size_t)au[b] * NH + hc];
  }
  __syncthreads();
  int v = blockIdx.x * 256 + tid;
  if (v >= NV) return;
  float acc[16];
  #pragma unroll
  for (int b = 0; b < 16; b++) acc[b] = 0.f;
  const float* wrow = fcW + (size_t)v * 768 + 512;
  for (int hc = 0; hc < 256; hc += 4){
    float4 w4 = *(const float4*)(wrow + hc);
    #pragma unroll
    for (int b = 0; b < 16; b++){
      acc[b] += w4.x * pl[b*256+hc] + w4.y * pl[b*256+hc+1]
              + w4.z * pl[b*256+hc+2] + w4.w * pl[b*256+hc+3];
    }
  }
  float fb = fcb[v];
  #pragma unroll
  for (int b = 0; b < 16; b++) ulog[(size_t)b * NV + v] = acc[b] + fb;
}

// batched bf16 transpose: src [z][R][C] -> dst [z][C][R]
__global__ __launch_bounds__(256) void k_transpose(const ushort_t* __restrict__ src,
    ushort_t* __restrict__ dst, int R, int C, long long sstride, long long dstride){
  __shared__ ushort_t tile[32][33];
  int z = blockIdx.z;
  int c0 = blockIdx.x * 32, r0 = blockIdx.y * 32;
  int tx = threadIdx.x & 31, ty = threadIdx.x >> 5;
  const ushort_t* Sp = src + (size_t)sstride * z;
  ushort_t* Dp = dst + (size_t)dstride * z;
  #pragma unroll
  for (int i = 0; i < 32; i += 8) tile[ty+i][tx] = Sp[(size_t)(r0+ty+i) * C + c0 + tx];
  __syncthreads();
  #pragma unroll
  for (int i = 0; i < 32; i += 8) Dp[(size_t)(c0+ty+i) * R + r0 + tx] = tile[tx][ty+i];
}

// ---------------- generic bf16 MFMA GEMM: C[M][N] = A[M][K] * BT[N][K]^T ----------------
// cmode: 0 = fp32 store, 1 = bf16 store, 2 = bf16 store at row (mr*16+z) [ctx remap]
__global__ __launch_bounds__(256, 2) void k_gemm(
    const ushort_t* __restrict__ A, const ushort_t* __restrict__ Bt, void* __restrict__ Cp,
    int M, int N, int K, int lda, int ldb, int ldc,
    long long sAz, long long sBz, long long sCz,
    const float* __restrict__ bias,
    const float* __restrict__ rowscale, int rsStride,
    const float* __restrict__ addrow, int ldu,
    float cscale, int cmode){
  __shared__ __align__(16) ushort_t As[128 * 40];
  __shared__ __align__(16) ushort_t Bs[128 * 40];
  int z = blockIdx.z;
  int n0 = blockIdx.x * 128, m0 = blockIdx.y * 128;
  int tid = threadIdx.x;
  int wave = tid >> 6, lane = tid & 63;
  int l15 = lane & 15, q4 = lane >> 4;
  int wm = (wave >> 1) * 64, wn = (wave & 1) * 64;
  const ushort_t* Ab = A + (size_t)sAz * z;
  const ushort_t* Bb = Bt + (size_t)sBz * z;
  // full-tile staging: 128 rows x 32 k-elems = 4096; 256 thr x 16 elems
  int srow = tid >> 1, scol = (tid & 1) * 16;
  f32x4 acc[4][4];
  #pragma unroll
  for (int tm = 0; tm < 4; tm++)
    #pragma unroll
    for (int tn = 0; tn < 4; tn++) acc[tm][tn] = (f32x4){0.f,0.f,0.f,0.f};

  for (int k0 = 0; k0 < K; k0 += 32){
    __syncthreads();
    const ushort_t* ap = Ab + (size_t)(m0+srow)*lda + k0 + scol;
    const ushort_t* bp = Bb + (size_t)(n0+srow)*ldb + k0 + scol;
    *(uint4*)&As[srow*40 + scol]     = *(const uint4*)ap;
    *(uint4*)&As[srow*40 + scol + 8] = *(const uint4*)(ap + 8);
    *(uint4*)&Bs[srow*40 + scol]     = *(const uint4*)bp;
    *(uint4*)&Bs[srow*40 + scol + 8] = *(const uint4*)(bp + 8);
    __syncthreads();
    short8 af[4], bf[4];
    #pragma unroll
    for (int tm = 0; tm < 4; tm++) af[tm] = *(const short8*)&As[(wm + tm*16 + l15)*40 + q4*8];
    #pragma unroll
    for (int tn = 0; tn < 4; tn++) bf[tn] = *(const short8*)&Bs[(wn + tn*16 + l15)*40 + q4*8];
    #pragma unroll
    for (int tm = 0; tm < 4; tm++)
      #pragma unroll
      for (int tn = 0; tn < 4; tn++)
        acc[tm][tn] = __builtin_amdgcn_mfma_f32_16x16x32_bf16(af[tm], bf[tn], acc[tm][tn], 0, 0, 0);
  }

  #pragma unroll
  for (int tm = 0; tm < 4; tm++)
    #pragma unroll
    for (int tn = 0; tn < 4; tn++)
      #pragma unroll
      for (int r = 0; r < 4; r++){
        int mr = m0 + wm + tm*16 + q4*4 + r;
        int nc = n0 + wn + tn*16 + l15;
        if (nc < N){
          float v = acc[tm][tn][r] * cscale;
          if (bias)     v += bias[nc];
          if (rowscale) v *= rowscale[(size_t)z * rsStride + mr];
          if (addrow)   v += addrow[(size_t)(mr & 15) * ldu + nc];
          if (cmode == 0){
            ((float*)Cp)[(size_t)sCz * z + (size_t)mr * ldc + nc] = v;
          } else if (cmode == 1){
            ((ushort_t*)Cp)[(size_t)sCz * z + (size_t)mr * ldc + nc] = f2bf(v);
          } else {
            ((ushort_t*)Cp)[((size_t)mr * 16 + z) * ldc + nc] = f2bf(v);
          }
        }
      }
}

// ---------------- sequential RNN (fwd+bwd), Whh resident in VGPRs ----------------
// grid = 4 blocks: blockIdx.x = dir*2 + half (8 batches per workgroup)
//
// Latency-optimized recurrence:
//  - double-buffered h in LDS -> ONE barrier per step
//  - raw s_barrier + lgkmcnt-only wait (no vmcnt drain: outf stores & xW
//    prefetch loads stay in flight across the barrier)
//  - epilogue split across duplicate lane groups: q4 in {0,1} handle tn {0,1},
//    q4 in {2,3} hold the same batch rows (A rows are lane&7-duplicated) and
//    handle tn {2,3} -> 8 transcendentals/stores per lane instead of 16 on half
//  - xW prefetch distance 2 (even/odd register sets, no rotation copies), so
//    the vmcnt wait for the stream lands ~2 steps after issue (HBM covered)
__global__ __launch_bounds__(256, 1) void k_rnn(
    const float* __restrict__ WhhF, const float* __restrict__ WhhB,
    const float* __restrict__ xWf, const float* __restrict__ xWb,
    const float* __restrict__ h0,
    ushort_t* __restrict__ outf,     // [16][512][256] bf16 (fwd dir only)
    float* __restrict__ hout){       // [2][16][256] fp32
  int dir = blockIdx.x >> 1, half = blockIdx.x & 1;
  const float* Whh = dir ? WhhB : WhhF;
  const float* xW  = dir ? xWb : xWf;
  int tid = threadIdx.x, wave = tid >> 6, lane = tid & 63;
  int l15 = lane & 15, q4 = lane >> 4;
  __shared__ __align__(16) ushort_t hl[2][8 * 264];

  for (int idx = tid; idx < 2048; idx += 256){
    int m = idx >> 8, n = idx & 255;
    hl[0][m*264 + n] = f2bf(h0[((size_t)dir * 16 + half * 8 + m) * NH + n]);
  }

  short8 bfr[4][8];   // Whh^T B-fragments, resident
  #pragma unroll
  for (int tn = 0; tn < 4; tn++)
    #pragma unroll
    for (int kk = 0; kk < 8; kk++){
      int n = wave*64 + tn*16 + l15;
      int k = kk*32 + q4*8;
      const float* wp = Whh + (size_t)n * NH + k;
      float4 wa = *(const float4*)wp, wb2 = *(const float4*)(wp + 4);
      short8 f;
      f[0]=(short)f2bf(wa.x); f[1]=(short)f2bf(wa.y); f[2]=(short)f2bf(wa.z); f[3]=(short)f2bf(wa.w);
      f[4]=(short)f2bf(wb2.x); f[5]=(short)f2bf(wb2.y); f[6]=(short)f2bf(wb2.z); f[7]=(short)f2bf(wb2.w);
      bfr[tn][kk] = f;
    }

  // per-lane epilogue assignment
  int hiTn  = q4 >> 1;                         // 0: tn {0,1}; 1: tn {2,3}
  int mb    = (q4 & 1) * 4;                    // batch row base (rows duplicated)
  int ncol0 = wave*64 + hiTn*32 + l15;         // col for ti=0; ti=1 is +16

  // xW prefetch, distance 2: even steps use xwE, odd use xwO
  float xwE[8], xwO[8];
  #pragma unroll
  for (int r = 0; r < 4; r++){
    xwE[r]   = xW[(size_t)(half*8 + mb + r) * NH + ncol0];
    xwE[4+r] = xW[(size_t)(half*8 + mb + r) * NH + ncol0 + 16];
    xwO[r]   = xW[(size_t)(16 + half*8 + mb + r) * NH + ncol0];
    xwO[4+r] = xW[(size_t)(16 + half*8 + mb + r) * NH + ncol0 + 16];
  }
  __syncthreads();   // h0 + bfr staging complete (full drain once is fine)

#define RNN_STEP(S_, RB_, WB_, XWU_)                                              \
  {                                                                               \
    short8 af[8];                                                                 \
    _Pragma("unroll")                                                             \
    for (int kk = 0; kk < 8; kk++)                                                \
      af[kk] = *(const short8*)&hl[RB_][(lane & 7)*264 + kk*32 + q4*8];           \
    f32x4 acc0 = (f32x4){0.f,0.f,0.f,0.f}, acc1 = acc0, acc2 = acc0, acc3 = acc0; \
    _Pragma("unroll")                                                             \
    for (int kk = 0; kk < 8; kk++){                                               \
      acc0 = __builtin_amdgcn_mfma_f32_16x16x32_bf16(af[kk], bfr[0][kk], acc0, 0,0,0); \
      acc1 = __builtin_amdgcn_mfma_f32_16x16x32_bf16(af[kk], bfr[1][kk], acc1, 0,0,0); \
      acc2 = __builtin_amdgcn_mfma_f32_16x16x32_bf16(af[kk], bfr[2][kk], acc2, 0,0,0); \
      acc3 = __builtin_amdgcn_mfma_f32_16x16x32_bf16(af[kk], bfr[3][kk], acc3, 0,0,0); \
    }                                                                             \
    f32x4 accA = hiTn ? acc2 : acc0;                                              \
    f32x4 accB = hiTn ? acc3 : acc1;                                              \
    _Pragma("unroll")                                                             \
    for (int r = 0; r < 4; r++){                                                  \
      float pre0 = accA[r] + XWU_[r];                                             \
      float pre1 = accB[r] + XWU_[4+r];                                           \
      float ex0 = __expf(2.f * pre0), ex1 = __expf(2.f * pre1);                   \
      float hv0 = 1.f - 2.f * __builtin_amdgcn_rcpf(ex0 + 1.f);                   \
      float hv1 = 1.f - 2.f * __builtin_amdgcn_rcpf(ex1 + 1.f);                   \
      int m = mb + r;                                                             \
      ushort_t hb0 = f2bf(hv0), hb1 = f2bf(hv1);                                  \
      hl[WB_][m*264 + ncol0]      = hb0;                                          \
      hl[WB_][m*264 + ncol0 + 16] = hb1;                                          \
      if (dir == 0){                                                              \
        outf[((size_t)(half*8+m) * 512 + (S_)) * NH + ncol0]      = hb0;          \
        outf[((size_t)(half*8+m) * 512 + (S_)) * NH + ncol0 + 16] = hb1;          \
      }                                                                           \
      if ((S_) == 511){                                                           \
        hout[((size_t)dir*16 + half*8 + m) * NH + ncol0]      = hv0;              \
        hout[((size_t)dir*16 + half*8 + m) * NH + ncol0 + 16] = hv1;              \
      }                                                                           \
    }                                                                             \
    if ((S_) < 510){                                                              \
      _Pragma("unroll")                                                           \
      for (int r = 0; r < 4; r++){                                                \
        XWU_[r]   = xW[((size_t)((S_)+2)*16 + half*8 + mb + r) * NH + ncol0];     \
        XWU_[4+r] = xW[((size_t)((S_)+2)*16 + half*8 + mb + r) * NH + ncol0 + 16];\
      }                                                                           \
    }                                                                             \
    asm volatile("s_waitcnt lgkmcnt(0)" ::: "memory");                            \
    __builtin_amdgcn_s_barrier();                                                 \
    asm volatile("" ::: "memory");                                                \
  }

  for (int s = 0; s < 512; s += 2){
    RNN_STEP(s,     0, 1, xwE)
    RNN_STEP(s + 1, 1, 0, xwO)
  }
#undef RNN_STEP
}

// ---------------- row softmax: fp32 scores [z][512][512] -> bf16 alpha ----------------
__global__ __launch_bounds__(256) void k_softmax(const float* __restrict__ sc,
                                                 ushort_t* __restrict__ alpha){
  int q = blockIdx.x, z = blockIdx.y, tid = threadIdx.x;
  const float* row = sc + ((size_t)z * S_LEN + q) * S_LEN;
  float v0 = row[tid], v1 = row[tid + 256];
  __shared__ float red[256];
  red[tid] = fmaxf(v0, v1); __syncthreads();
  for (int st = 128; st > 0; st >>= 1){
    if (tid < st) red[tid] = fmaxf(red[tid], red[tid + st]);
    __syncthreads();
  }
  float mx = red[0]; __syncthreads();
  float e0 = __expf(v0 - mx), e1 = __expf(v1 - mx);
  red[tid] = e0 + e1; __syncthreads();
  for (int st = 128; st > 0; st >>= 1){
    if (tid < st) red[tid] += red[tid + st];
    __syncthreads();
  }
  float inv = 1.f / red[0];
  ushort_t* arow = alpha + ((size_t)z * S_LEN + q) * S_LEN;
  arow[tid]       = f2bf(e0 * inv);
  arow[tid + 256] = f2bf(e1 * inv);
}

// ---------------- launch ----------------
extern "C" void kernel_launch(void* const* d_in, const int* in_sizes, int n_in,
                              void* d_out, int out_size, void* d_ws, size_t ws_size,
                              hipStream_t stream){
  const int*   x    = (const int*)d_in[0];
  const float* t    = (const float*)d_in[1];
  const float* s2   = (const float*)d_in[2];
  const float* h0   = (const float*)d_in[5];
  const int*   au   = (const int*)d_in[6];
  const float* emb  = (const float*)d_in[7];
  const float* uemb = (const float*)d_in[8];
  const float* WihF = (const float*)d_in[9];
  const float* WhhF = (const float*)d_in[10];
  const float* bF   = (const float*)d_in[11];
  const float* WihB = (const float*)d_in[12];
  const float* WhhB = (const float*)d_in[13];
  const float* bB   = (const float*)d_in[14];
  const float* fcW  = (const float*)d_in[15];
  const float* fcb  = (const float*)d_in[16];
  float* y    = (float*)d_out;
  float* hout = y + (size_t)S_LEN * NB * NV;

  char* wsc = (char*)d_ws;
  size_t off = 0;
  auto alloc = [&](size_t bytes) -> void* {
    void* p = wsc + off;
    off += (bytes + 255) & ~(size_t)255;
    return p;
  };
  ushort_t* xe    = (ushort_t*)alloc(8192 * 256 * 2);
  ushort_t* xer   = (ushort_t*)alloc(8192 * 256 * 2);
  ushort_t* wihf  = (ushort_t*)alloc(256 * 256 * 2);
  ushort_t* wihb  = (ushort_t*)alloc(256 * 256 * 2);
  float*    xwf   = (float*)alloc((size_t)8192 * 256 * 4);   // reused as scores (with xwb)
  float*    xwb   = (float*)alloc((size_t)8192 * 256 * 4);
  ushort_t* outf  = (ushort_t*)alloc((size_t)16 * 512 * 256 * 2);
  ushort_t* outfT = (ushort_t*)alloc((size_t)16 * 256 * 512 * 2);
  ushort_t* wbuf  = (ushort_t*)alloc((size_t)16 * 512 * 512 * 2);  // reused as alpha
  float*    rsum  = (float*)alloc(16 * 512 * 4);
  ushort_t* owf   = (ushort_t*)alloc((size_t)16 * 512 * 256 * 2);
  ushort_t* owfT  = (ushort_t*)alloc((size_t)16 * 256 * 512 * 2);
  ushort_t* fcw1  = (ushort_t*)alloc((size_t)10112 * 256 * 2);
  float*    ulog  = (float*)alloc((size_t)16 * NV * 4);
  float*    tT    = (float*)alloc(16 * 512 * 4);
  float*    sxT   = (float*)alloc(16 * 512 * 4);
  float*    syT   = (float*)alloc(16 * 512 * 4);
  ushort_t* ctx   = (ushort_t*)alloc((size_t)8192 * 256 * 2);
  float*    scores = xwf;          // 16.78 MB, xW dead after k_rnn (xwf+xwb contiguous)
  ushort_t* alpha  = wbuf;         // w dead after stage C

  // prep
  k_prep_xemb<<<dim3(1024), dim3(256), 0, stream>>>(x, emb, xe, xer);
  k_cvt<<<dim3(32), dim3(256), 0, stream>>>(WihF, wihf, 65536);
  k_cvt<<<dim3(32), dim3(256), 0, stream>>>(WihB, wihb, 65536);
  k_prep_fcw<<<dim3(1264), dim3(256), 0, stream>>>(fcW, fcw1);
  k_prep_tsT<<<dim3(32), dim3(256), 0, stream>>>(t, s2, tT, sxT, syT);
  k_prep_w<<<dim3(512, 16), dim3(256), 0, stream>>>(tT, sxT, syT, wbuf, rsum);
  k_ulog<<<dim3(40), dim3(256), 0, stream>>>(au, uemb, fcW, fcb, ulog);

  // xW = x_emb @ Wih^T + b   (fwd and reversed)
  k_gemm<<<dim3(2, 64, 1), dim3(256), 0, stream>>>(xe, wihf, xwf,
      8192, 256, 256, 256, 256, 256, 0, 0, 0, bF, nullptr, 0, nullptr, 0, 1.f, 0);
  k_gemm<<<dim3(2, 64, 1), dim3(256), 0, stream>>>(xer, wihb, xwb,
      8192, 256, 256, 256, 256, 256, 0, 0, 0, bB, nullptr, 0, nullptr, 0, 1.f, 0);

  // sequential RNNs
  k_rnn<<<dim3(4), dim3(256), 0, stream>>>(WhhF, WhhB, xwf, xwb, h0, outf, hout);

  // out_f [b][s][h] -> [b][h][s]
  k_transpose<<<dim3(8, 16, 16), dim3(256), 0, stream>>>(outf, outfT, 512, 256,
      (long long)512 * 256, (long long)256 * 512);

  // stage C: out_w = (w @ out_f) / sum_w   -> bf16 [b][512][256]
  k_gemm<<<dim3(2, 4, 16), dim3(256), 0, stream>>>(wbuf, outfT, owf,
      512, 256, 512, 512, 512, 256,
      (long long)512 * 512, (long long)256 * 512, (long long)512 * 256,
      nullptr, rsum, 512, nullptr, 0, 1.f, 1);
  k_transpose<<<dim3(8, 16, 16), dim3(256), 0, stream>>>(owf, owfT, 512, 256,
      (long long)512 * 256, (long long)256 * 512);

  // D1: scores = owf @ owf^T / sqrt(512)
  k_gemm<<<dim3(4, 4, 16), dim3(256), 0, stream>>>(owf, owf, scores,
      512, 512, 256, 256, 256, 512,
      (long long)512 * 256, (long long)512 * 256, (long long)512 * 512,
      nullptr, nullptr, 0, nullptr, 0, 0.04419417382415922f, 0);

  k_softmax<<<dim3(512, 16), dim3(256), 0, stream>>>(scores, alpha);

  // D2: ctx = alpha @ owf  -> bf16 remapped to rows (s*16+b)
  k_gemm<<<dim3(2, 4, 16), dim3(256), 0, stream>>>(alpha, owfT, ctx,
      512, 256, 512, 512, 512, 256,
      (long long)512 * 512, (long long)256 * 512, 0,
      nullptr, nullptr, 0, nullptr, 0, 1.f, 2);

  // E: y = ctx @ fcW1^T + ulog (+fc_b folded into ulog)
  k_gemm<<<dim3(79, 64, 1), dim3(256), 0, stream>>>(ctx, fcw1, y,
      8192, 10000, 256, 256, 256, 10000, 0, 0, 0,
      nullptr, nullptr, 0, ulog, 10000, 1.f, 0);
}

// Round 2
// 966.073 us; speedup vs baseline: 1.4966x; 1.1587x over previous
//
#include <hip/hip_runtime.h>

typedef unsigned short ushort_t;
typedef __attribute__((ext_vector_type(8))) short short8;
typedef __attribute__((ext_vector_type(4))) float f32x4;

#define S_LEN 512
#define NB 16
#define NH 256
#define NV 10000

__device__ __forceinline__ unsigned short f2bf(float f){
  unsigned u = __float_as_uint(f);
  u += 0x7fffu + ((u >> 16) & 1u);          // RNE to bf16
  return (unsigned short)(u >> 16);
}

// ---------------- prep kernels ----------------

// x_emb gather + bf16 cvt, plus sequence-reversed copy for the backward RNN.
__global__ __launch_bounds__(256) void k_prep_xemb(const int* __restrict__ x,
    const float* __restrict__ emb, ushort_t* __restrict__ xe, ushort_t* __restrict__ xer){
  int g = blockIdx.x * 256 + threadIdx.x;      // 8192 rows * 32 chunks
  int m = g >> 5, c = (g & 31) << 3;
  int xm = x[m];
  const float* src = emb + (size_t)xm * NH + c;
  float4 a = *(const float4*)src, b = *(const float4*)(src + 4);
  union { ushort_t us[8]; uint4 v; } u;
  u.us[0]=f2bf(a.x); u.us[1]=f2bf(a.y); u.us[2]=f2bf(a.z); u.us[3]=f2bf(a.w);
  u.us[4]=f2bf(b.x); u.us[5]=f2bf(b.y); u.us[6]=f2bf(b.z); u.us[7]=f2bf(b.w);
  int s = m >> 4, bidx = m & 15;
  int mr = ((S_LEN - 1 - s) << 4) | bidx;
  *(uint4*)&xe [(size_t)m  * NH + c] = u.v;
  *(uint4*)&xer[(size_t)mr * NH + c] = u.v;
}

__global__ __launch_bounds__(256) void k_cvt(const float* __restrict__ src,
                                             ushort_t* __restrict__ dst, int n){
  int g = (blockIdx.x * 256 + threadIdx.x) * 8;
  if (g >= n) return;
  float4 a = *(const float4*)(src + g), b = *(const float4*)(src + g + 4);
  union { ushort_t us[8]; uint4 v; } u;
  u.us[0]=f2bf(a.x); u.us[1]=f2bf(a.y); u.us[2]=f2bf(a.z); u.us[3]=f2bf(a.w);
  u.us[4]=f2bf(b.x); u.us[5]=f2bf(b.y); u.us[6]=f2bf(b.z); u.us[7]=f2bf(b.w);
  *(uint4*)&dst[g] = u.v;
}

// fc_W[:, 0:256] -> bf16 [10112][256] (rows >= 10000 zero-padded)
__global__ __launch_bounds__(256) void k_prep_fcw(const float* __restrict__ fcW,
                                                  ushort_t* __restrict__ out){
  int g = blockIdx.x * 256 + threadIdx.x;      // 10112*32
  int v = g >> 5, c = (g & 31) << 3;
  union { ushort_t us[8]; uint4 q; } u;
  if (v < NV){
    const float* p = fcW + (size_t)v * 768 + c;
    float4 a = *(const float4*)p, b = *(const float4*)(p + 4);
    u.us[0]=f2bf(a.x); u.us[1]=f2bf(a.y); u.us[2]=f2bf(a.z); u.us[3]=f2bf(a.w);
    u.us[4]=f2bf(b.x); u.us[5]=f2bf(b.y); u.us[6]=f2bf(b.z); u.us[7]=f2bf(b.w);
  } else {
    u.q = make_uint4(0,0,0,0);
  }
  *(uint4*)&out[(size_t)v * NH + c] = u.q;
}

__global__ __launch_bounds__(256) void k_prep_tsT(const float* __restrict__ t,
    const float* __restrict__ s2, float* __restrict__ tT,
    float* __restrict__ sxT, float* __restrict__ syT){
  int g = blockIdx.x * 256 + threadIdx.x;   // 8192 = 512*16
  int j = g >> 4, b = g & 15;
  tT [b * S_LEN + j] = t[g];
  sxT[b * S_LEN + j] = s2[(size_t)g * 2];
  syT[b * S_LEN + j] = s2[(size_t)g * 2 + 1];
}

// pairwise decay weights: w bf16 [b][i][j] (0 for j>i), rsum = 1/sum_j w
__global__ __launch_bounds__(256) void k_prep_w(const float* __restrict__ tT,
    const float* __restrict__ sxT, const float* __restrict__ syT,
    ushort_t* __restrict__ wb, float* __restrict__ rsum){
  int i = blockIdx.x, b = blockIdx.y, tid = threadIdx.x;
  const float C1 = 7.272205216643040e-05f;   // 2*pi/86400
  const float C2 = -1.1574074074074074e-06f; // -0.1/86400
  float ti = tT[b*S_LEN+i], sxi = sxT[b*S_LEN+i], syi = syT[b*S_LEN+i];
  __shared__ float red[256];
  float psum = 0.f;
  #pragma unroll
  for (int u2 = 0; u2 < 2; u2++){
    int j = tid + u2 * 256;
    float w = 0.f;
    if (j <= i){
      float dt = ti - tT[b*S_LEN+j];
      float dx = sxi - sxT[b*S_LEN+j], dy = syi - syT[b*S_LEN+j];
      float ds = sqrtf(dx*dx + dy*dy);
      float a = (__cosf(dt * C1) + 1.f) * 0.5f * __expf(dt * C2);
      float bw = __expf(-100.f * ds);
      w = a * bw + 1e-10f;
    }
    psum += w;
    wb[((size_t)b * S_LEN + i) * S_LEN + j] = f2bf(w);
  }
  red[tid] = psum; __syncthreads();
  for (int st = 128; st > 0; st >>= 1){
    if (tid < st) red[tid] += red[tid + st];
    __syncthreads();
  }
  if (tid == 0) rsum[b * S_LEN + i] = 1.f / red[0];
}

// ulog[b][v] = p_u[b] . fc_W[v][512:768] + fc_b[v]
__global__ __launch_bounds__(256) void k_ulog(const int* __restrict__ au,
    const float* __restrict__ uemb, const float* __restrict__ fcW,
    const float* __restrict__ fcb, float* __restrict__ ulog){
  __shared__ float pl[16 * 256];
  int tid = threadIdx.x;
  for (int idx = tid; idx < 16 * 256; idx += 256){
    int b = idx >> 8, hc = idx & 255;
    pl[idx] = uemb[(size_t)au[b] * NH + hc];
  }
  __syncthreads();
  int v = blockIdx.x * 256 + tid;
  if (v >= NV) return;
  float acc[16];
  #pragma unroll
  for (int b = 0; b < 16; b++) acc[b] = 0.f;
  const float* wrow = fcW + (size_t)v * 768 + 512;
  for (int hc = 0; hc < 256; hc += 4){
    float4 w4 = *(const float4*)(wrow + hc);
    #pragma unroll
    for (int b = 0; b < 16; b++){
      acc[b] += w4.x * pl[b*256+hc] + w4.y * pl[b*256+hc+1]
              + w4.z * pl[b*256+hc+2] + w4.w * pl[b*256+hc+3];
    }
  }
  float fb = fcb[v];
  #pragma unroll
  for (int b = 0; b < 16; b++) ulog[(size_t)b * NV + v] = acc[b] + fb;
}

// batched bf16 transpose: src [z][R][C] -> dst [z][C][R]
__global__ __launch_bounds__(256) void k_transpose(const ushort_t* __restrict__ src,
    ushort_t* __restrict__ dst, int R, int C, long long sstride, long long dstride){
  __shared__ ushort_t tile[32][33];
  int z = blockIdx.z;
  int c0 = blockIdx.x * 32, r0 = blockIdx.y * 32;
  int tx = threadIdx.x & 31, ty = threadIdx.x >> 5;
  const ushort_t* Sp = src + (size_t)sstride * z;
  ushort_t* Dp = dst + (size_t)dstride * z;
  #pragma unroll
  for (int i = 0; i < 32; i += 8) tile[ty+i][tx] = Sp[(size_t)(r0+ty+i) * C + c0 + tx];
  __syncthreads();
  #pragma unroll
  for (int i = 0; i < 32; i += 8) Dp[(size_t)(c0+ty+i) * R + r0 + tx] = tile[tx][ty+i];
}

// ---------------- generic bf16 MFMA GEMM: C[M][N] = A[M][K] * BT[N][K]^T ----------------
// cmode: 0 = fp32 store, 1 = bf16 store, 2 = bf16 store at row (mr*16+z) [ctx remap]
__global__ __launch_bounds__(256, 2) void k_gemm(
    const ushort_t* __restrict__ A, const ushort_t* __restrict__ Bt, void* __restrict__ Cp,
    int M, int N, int K, int lda, int ldb, int ldc,
    long long sAz, long long sBz, long long sCz,
    const float* __restrict__ bias,
    const float* __restrict__ rowscale, int rsStride,
    const float* __restrict__ addrow, int ldu,
    float cscale, int cmode){
  __shared__ __align__(16) ushort_t As[128 * 40];
  __shared__ __align__(16) ushort_t Bs[128 * 40];
  int z = blockIdx.z;
  int n0 = blockIdx.x * 128, m0 = blockIdx.y * 128;
  int tid = threadIdx.x;
  int wave = tid >> 6, lane = tid & 63;
  int l15 = lane & 15, q4 = lane >> 4;
  int wm = (wave >> 1) * 64, wn = (wave & 1) * 64;
  const ushort_t* Ab = A + (size_t)sAz * z;
  const ushort_t* Bb = Bt + (size_t)sBz * z;
  // full-tile staging: 128 rows x 32 k-elems = 4096; 256 thr x 16 elems
  int srow = tid >> 1, scol = (tid & 1) * 16;
  f32x4 acc[4][4];
  #pragma unroll
  for (int tm = 0; tm < 4; tm++)
    #pragma unroll
    for (int tn = 0; tn < 4; tn++) acc[tm][tn] = (f32x4){0.f,0.f,0.f,0.f};

  for (int k0 = 0; k0 < K; k0 += 32){
    __syncthreads();
    const ushort_t* ap = Ab + (size_t)(m0+srow)*lda + k0 + scol;
    const ushort_t* bp = Bb + (size_t)(n0+srow)*ldb + k0 + scol;
    *(uint4*)&As[srow*40 + scol]     = *(const uint4*)ap;
    *(uint4*)&As[srow*40 + scol + 8] = *(const uint4*)(ap + 8);
    *(uint4*)&Bs[srow*40 + scol]     = *(const uint4*)bp;
    *(uint4*)&Bs[srow*40 + scol + 8] = *(const uint4*)(bp + 8);
    __syncthreads();
    short8 af[4], bf[4];
    #pragma unroll
    for (int tm = 0; tm < 4; tm++) af[tm] = *(const short8*)&As[(wm + tm*16 + l15)*40 + q4*8];
    #pragma unroll
    for (int tn = 0; tn < 4; tn++) bf[tn] = *(const short8*)&Bs[(wn + tn*16 + l15)*40 + q4*8];
    #pragma unroll
    for (int tm = 0; tm < 4; tm++)
      #pragma unroll
      for (int tn = 0; tn < 4; tn++)
        acc[tm][tn] = __builtin_amdgcn_mfma_f32_16x16x32_bf16(af[tm], bf[tn], acc[tm][tn], 0, 0, 0);
  }

  #pragma unroll
  for (int tm = 0; tm < 4; tm++)
    #pragma unroll
    for (int tn = 0; tn < 4; tn++)
      #pragma unroll
      for (int r = 0; r < 4; r++){
        int mr = m0 + wm + tm*16 + q4*4 + r;
        int nc = n0 + wn + tn*16 + l15;
        if (nc < N){
          float v = acc[tm][tn][r] * cscale;
          if (bias)     v += bias[nc];
          if (rowscale) v *= rowscale[(size_t)z * rsStride + mr];
          if (addrow)   v += addrow[(size_t)(mr & 15) * ldu + nc];
          if (cmode == 0){
            ((float*)Cp)[(size_t)sCz * z + (size_t)mr * ldc + nc] = v;
          } else if (cmode == 1){
            ((ushort_t*)Cp)[(size_t)sCz * z + (size_t)mr * ldc + nc] = f2bf(v);
          } else {
            ((ushort_t*)Cp)[((size_t)mr * 16 + z) * ldc + nc] = f2bf(v);
          }
        }
      }
}

// ---------------- sequential RNN (fwd+bwd), Whh resident in VGPRs ----------------
// grid = 4 blocks: blockIdx.x = dir*2 + half (8 batches per workgroup)
//
// v3: 8 waves x 512 threads (2 waves/SIMD) so latencies cross-cover.
//  - each wave owns a 32-wide N slice: 16 MFMA/step/wave, 2 MFMA chains
//  - every lane does a 4-value epilogue (no idle lanes)
//  - double-buffered h in LDS, ONE raw s_barrier + lgkmcnt(0) per step
//    (outf stores & xW prefetch loads stay in flight across the barrier)
//  - xW prefetch distance 2 via one step-bumped pointer + imm offsets
//  - outf stores via 4 step-bumped pointers (no per-step address mults)
__global__ __launch_bounds__(512, 1) void k_rnn(
    const float* __restrict__ WhhF, const float* __restrict__ WhhB,
    const float* __restrict__ xWf, const float* __restrict__ xWb,
    const float* __restrict__ h0,
    ushort_t* __restrict__ outf,     // [16][512][256] bf16 (fwd dir only)
    float* __restrict__ hout){       // [2][16][256] fp32
  int dir = blockIdx.x >> 1, half = blockIdx.x & 1;
  const float* Whh = dir ? WhhB : WhhF;
  const float* xW  = dir ? xWb : xWf;
  int tid = threadIdx.x, wave = tid >> 6, lane = tid & 63;
  int l15 = lane & 15, q4 = lane >> 4;
  __shared__ __align__(16) ushort_t hl[2][8 * 264];

  for (int idx = tid; idx < 2048; idx += 512){
    int m = idx >> 8, n = idx & 255;
    hl[0][m*264 + n] = f2bf(h0[((size_t)dir * 16 + half * 8 + m) * NH + n]);
  }

  short8 bfr[2][8];   // Whh^T B-fragments, resident (wave's 32-col slice)
  #pragma unroll
  for (int tn = 0; tn < 2; tn++)
    #pragma unroll
    for (int kk = 0; kk < 8; kk++){
      int n = wave*32 + tn*16 + l15;
      int k = kk*32 + q4*8;
      const float* wp = Whh + (size_t)n * NH + k;
      float4 wa = *(const float4*)wp, wb2 = *(const float4*)(wp + 4);
      short8 f;
      f[0]=(short)f2bf(wa.x); f[1]=(short)f2bf(wa.y); f[2]=(short)f2bf(wa.z); f[3]=(short)f2bf(wa.w);
      f[4]=(short)f2bf(wb2.x); f[5]=(short)f2bf(wb2.y); f[6]=(short)f2bf(wb2.z); f[7]=(short)f2bf(wb2.w);
      bfr[tn][kk] = f;
    }

  // per-lane epilogue assignment: 4 values = rows mb..mb+3 of col ncol
  int myTn = q4 >> 1;                          // acc tile: 0 or 1
  int mb   = (q4 & 1) * 4;                     // batch row base (acc rows duplicated)
  int ncol = wave*32 + myTn*16 + l15;

  // xW prefetch, distance 2: even steps use xwE, odd use xwO; one bumped pointer
  const float* xwp = xW + (size_t)(half*8 + mb) * NH + ncol;
  float xwE[4], xwO[4];
  #pragma unroll
  for (int r = 0; r < 4; r++){
    xwE[r] = xwp[r * 256];                 // step 0
    xwO[r] = xwp[r * 256 + 16 * 256];      // step 1
  }
  xwp += 2 * 16 * 256;                     // -> step 2

  // outf store pointers (dir 0 only), bumped by 256 elems (one step) each step
  ushort_t* outp0 = outf + (size_t)(half*8 + mb) * 512 * NH + ncol;
  ushort_t* outp1 = outp0 + (size_t)512 * NH;
  ushort_t* outp2 = outp1 + (size_t)512 * NH;
  ushort_t* outp3 = outp2 + (size_t)512 * NH;

  __syncthreads();   // h0 + bfr staging complete (full drain once is fine)

#define RNN_STEP(S_, RB_, WB_, XWU_)                                              \
  {                                                                               \
    short8 af[8];                                                                 \
    _Pragma("unroll")                                                             \
    for (int kk = 0; kk < 8; kk++)                                                \
      af[kk] = *(const short8*)&hl[RB_][(lane & 7)*264 + kk*32 + q4*8];           \
    f32x4 acc0 = (f32x4){0.f,0.f,0.f,0.f}, acc1 = acc0;                           \
    _Pragma("unroll")                                                             \
    for (int kk = 0; kk < 8; kk++){                                               \
      acc0 = __builtin_amdgcn_mfma_f32_16x16x32_bf16(af[kk], bfr[0][kk], acc0, 0,0,0); \
      acc1 = __builtin_amdgcn_mfma_f32_16x16x32_bf16(af[kk], bfr[1][kk], acc1, 0,0,0); \
    }                                                                             \
    f32x4 accS = myTn ? acc1 : acc0;                                              \
    float hv[4];                                                                  \
    _Pragma("unroll")                                                             \
    for (int r = 0; r < 4; r++){                                                  \
      float pre = accS[r] + XWU_[r];                                              \
      float ex = __expf(2.f * pre);                                               \
      hv[r] = 1.f - 2.f * __builtin_amdgcn_rcpf(ex + 1.f);                        \
      hl[WB_][(mb + r)*264 + ncol] = f2bf(hv[r]);                                 \
    }                                                                             \
    if (dir == 0){                                                                \
      outp0[0] = f2bf(hv[0]); outp1[0] = f2bf(hv[1]);                             \
      outp2[0] = f2bf(hv[2]); outp3[0] = f2bf(hv[3]);                             \
      outp0 += 256; outp1 += 256; outp2 += 256; outp3 += 256;                     \
    }                                                                             \
    if ((S_) == 511){                                                             \
      _Pragma("unroll")                                                           \
      for (int r = 0; r < 4; r++)                                                 \
        hout[((size_t)dir*16 + half*8 + mb + r) * NH + ncol] = hv[r];             \
    }                                                                             \
    if ((S_) < 510){                                                              \
      _Pragma("unroll")                                                           \
      for (int r = 0; r < 4; r++) XWU_[r] = xwp[r * 256];                         \
      xwp += 16 * 256;                                                            \
    }                                                                             \
    asm volatile("s_waitcnt lgkmcnt(0)" ::: "memory");                            \
    __builtin_amdgcn_s_barrier();                                                 \
    asm volatile("" ::: "memory");                                                \
  }

  for (int s = 0; s < 512; s += 2){
    RNN_STEP(s,     0, 1, xwE)
    RNN_STEP(s + 1, 1, 0, xwO)
  }
#undef RNN_STEP
}

// ---------------- row softmax: fp32 scores [z][512][512] -> bf16 alpha ----------------
__global__ __launch_bounds__(256) void k_softmax(const float* __restrict__ sc,
                                                 ushort_t* __restrict__ alpha){
  int q = blockIdx.x, z = blockIdx.y, tid = threadIdx.x;
  const float* row = sc + ((size_t)z * S_LEN + q) * S_LEN;
  float v0 = row[tid], v1 = row[tid + 256];
  __shared__ float red[256];
  red[tid] = fmaxf(v0, v1); __syncthreads();
  for (int st = 128; st > 0; st >>= 1){
    if (tid < st) red[tid] = fmaxf(red[tid], red[tid + st]);
    __syncthreads();
  }
  float mx = red[0]; __syncthreads();
  float e0 = __expf(v0 - mx), e1 = __expf(v1 - mx);
  red[tid] = e0 + e1; __syncthreads();
  for (int st = 128; st > 0; st >>= 1){
    if (tid < st) red[tid] += red[tid + st];
    __syncthreads();
  }
  float inv = 1.f / red[0];
  ushort_t* arow = alpha + ((size_t)z * S_LEN + q) * S_LEN;
  arow[tid]       = f2bf(e0 * inv);
  arow[tid + 256] = f2bf(e1 * inv);
}

// ---------------- launch ----------------
extern "C" void kernel_launch(void* const* d_in, const int* in_sizes, int n_in,
                              void* d_out, int out_size, void* d_ws, size_t ws_size,
                              hipStream_t stream){
  const int*   x    = (const int*)d_in[0];
  const float* t    = (const float*)d_in[1];
  const float* s2   = (const float*)d_in[2];
  const float* h0   = (const float*)d_in[5];
  const int*   au   = (const int*)d_in[6];
  const float* emb  = (const float*)d_in[7];
  const float* uemb = (const float*)d_in[8];
  const float* WihF = (const float*)d_in[9];
  const float* WhhF = (const float*)d_in[10];
  const float* bF   = (const float*)d_in[11];
  const float* WihB = (const float*)d_in[12];
  const float* WhhB = (const float*)d_in[13];
  const float* bB   = (const float*)d_in[14];
  const float* fcW  = (const float*)d_in[15];
  const float* fcb  = (const float*)d_in[16];
  float* y    = (float*)d_out;
  float* hout = y + (size_t)S_LEN * NB * NV;

  char* wsc = (char*)d_ws;
  size_t off = 0;
  auto alloc = [&](size_t bytes) -> void* {
    void* p = wsc + off;
    off += (bytes + 255) & ~(size_t)255;
    return p;
  };
  ushort_t* xe    = (ushort_t*)alloc(8192 * 256 * 2);
  ushort_t* xer   = (ushort_t*)alloc(8192 * 256 * 2);
  ushort_t* wihf  = (ushort_t*)alloc(256 * 256 * 2);
  ushort_t* wihb  = (ushort_t*)alloc(256 * 256 * 2);
  float*    xwf   = (float*)alloc((size_t)8192 * 256 * 4);   // reused as scores (with xwb)
  float*    xwb   = (float*)alloc((size_t)8192 * 256 * 4);
  ushort_t* outf  = (ushort_t*)alloc((size_t)16 * 512 * 256 * 2);
  ushort_t* outfT = (ushort_t*)alloc((size_t)16 * 256 * 512 * 2);
  ushort_t* wbuf  = (ushort_t*)alloc((size_t)16 * 512 * 512 * 2);  // reused as alpha
  float*    rsum  = (float*)alloc(16 * 512 * 4);
  ushort_t* owf   = (ushort_t*)alloc((size_t)16 * 512 * 256 * 2);
  ushort_t* owfT  = (ushort_t*)alloc((size_t)16 * 256 * 512 * 2);
  ushort_t* fcw1  = (ushort_t*)alloc((size_t)10112 * 256 * 2);
  float*    ulog  = (float*)alloc((size_t)16 * NV * 4);
  float*    tT    = (float*)alloc(16 * 512 * 4);
  float*    sxT   = (float*)alloc(16 * 512 * 4);
  float*    syT   = (float*)alloc(16 * 512 * 4);
  ushort_t* ctx   = (ushort_t*)alloc((size_t)8192 * 256 * 2);
  float*    scores = xwf;          // 16.78 MB, xW dead after k_rnn (xwf+xwb contiguous)
  ushort_t* alpha  = wbuf;         // w dead after stage C

  // prep
  k_prep_xemb<<<dim3(1024), dim3(256), 0, stream>>>(x, emb, xe, xer);
  k_cvt<<<dim3(32), dim3(256), 0, stream>>>(WihF, wihf, 65536);
  k_cvt<<<dim3(32), dim3(256), 0, stream>>>(WihB, wihb, 65536);
  k_prep_fcw<<<dim3(1264), dim3(256), 0, stream>>>(fcW, fcw1);
  k_prep_tsT<<<dim3(32), dim3(256), 0, stream>>>(t, s2, tT, sxT, syT);
  k_prep_w<<<dim3(512, 16), dim3(256), 0, stream>>>(tT, sxT, syT, wbuf, rsum);
  k_ulog<<<dim3(40), dim3(256), 0, stream>>>(au, uemb, fcW, fcb, ulog);

  // xW = x_emb @ Wih^T + b   (fwd and reversed)
  k_gemm<<<dim3(2, 64, 1), dim3(256), 0, stream>>>(xe, wihf, xwf,
      8192, 256, 256, 256, 256, 256, 0, 0, 0, bF, nullptr, 0, nullptr, 0, 1.f, 0);
  k_gemm<<<dim3(2, 64, 1), dim3(256), 0, stream>>>(xer, wihb, xwb,
      8192, 256, 256, 256, 256, 256, 0, 0, 0, bB, nullptr, 0, nullptr, 0, 1.f, 0);

  // sequential RNNs
  k_rnn<<<dim3(4), dim3(512), 0, stream>>>(WhhF, WhhB, xwf, xwb, h0, outf, hout);

  // out_f [b][s][h] -> [b][h][s]
  k_transpose<<<dim3(8, 16, 16), dim3(256), 0, stream>>>(outf, outfT, 512, 256,
      (long long)512 * 256, (long long)256 * 512);

  // stage C: out_w = (w @ out_f) / sum_w   -> bf16 [b][512][256]
  k_gemm<<<dim3(2, 4, 16), dim3(256), 0, stream>>>(wbuf, outfT, owf,
      512, 256, 512, 512, 512, 256,
      (long long)512 * 512, (long long)256 * 512, (long long)512 * 256,
      nullptr, rsum, 512, nullptr, 0, 1.f, 1);
  k_transpose<<<dim3(8, 16, 16), dim3(256), 0, stream>>>(owf, owfT, 512, 256,
      (long long)512 * 256, (long long)256 * 512);

  // D1: scores = owf @ owf^T / sqrt(512)
  k_gemm<<<dim3(4, 4, 16), dim3(256), 0, stream>>>(owf, owf, scores,
      512, 512, 256, 256, 256, 512,
      (long long)512 * 256, (long long)512 * 256, (long long)512 * 512,
      nullptr, nullptr, 0, nullptr, 0, 0.04419417382415922f, 0);

  k_softmax<<<dim3(512, 16), dim3(256), 0, stream>>>(scores, alpha);

  // D2: ctx = alpha @ owf  -> bf16 remapped to rows (s*16+b)
  k_gemm<<<dim3(2, 4, 16), dim3(256), 0, stream>>>(alpha, owfT, ctx,
      512, 256, 512, 512, 512, 256,
      (long long)512 * 512, (long long)256 * 512, 0,
      nullptr, nullptr, 0, nullptr, 0, 1.f, 2);

  // E: y = ctx @ fcW1^T + ulog (+fc_b folded into ulog)
  k_gemm<<<dim3(79, 64, 1), dim3(256), 0, stream>>>(ctx, fcw1, y,
      8192, 10000, 256, 256, 256, 10000, 0, 0, 0,
      nullptr, nullptr, 0, ulog, 10000, 1.f, 0);
}

// Round 3
// 942.773 us; speedup vs baseline: 1.5336x; 1.0247x over previous
//
#include <hip/hip_runtime.h>

typedef unsigned short ushort_t;
typedef __attribute__((ext_vector_type(8))) short short8;
typedef __attribute__((ext_vector_type(4))) float f32x4;

#define S_LEN 512
#define NB 16
#define NH 256
#define NV 10000

__device__ __forceinline__ unsigned short f2bf(float f){
  unsigned u = __float_as_uint(f);
  u += 0x7fffu + ((u >> 16) & 1u);          // RNE to bf16
  return (unsigned short)(u >> 16);
}

// ---------------- fused prep 0: x_emb gather + Wih cvts ----------------
// bx < 512            : x_emb gather + bf16 cvt (+ reversed copy)
// 512 <= bx < 528     : WihF -> bf16
// 528 <= bx < 544     : WihB -> bf16
__global__ __launch_bounds__(512) void k_prep0(const int* __restrict__ x,
    const float* __restrict__ emb, ushort_t* __restrict__ xe, ushort_t* __restrict__ xer,
    const float* __restrict__ WihF, ushort_t* __restrict__ wihf,
    const float* __restrict__ WihB, ushort_t* __restrict__ wihb){
  int bx = blockIdx.x, tid = threadIdx.x;
  if (bx < 512){
    int g = bx * 512 + tid;                    // 8192 rows * 32 chunks
    int m = g >> 5, c = (g & 31) << 3;
    int xm = x[m];
    const float* src = emb + (size_t)xm * NH + c;
    float4 a = *(const float4*)src, b = *(const float4*)(src + 4);
    union { ushort_t us[8]; uint4 v; } u;
    u.us[0]=f2bf(a.x); u.us[1]=f2bf(a.y); u.us[2]=f2bf(a.z); u.us[3]=f2bf(a.w);
    u.us[4]=f2bf(b.x); u.us[5]=f2bf(b.y); u.us[6]=f2bf(b.z); u.us[7]=f2bf(b.w);
    int s = m >> 4, bidx = m & 15;
    int mr = ((S_LEN - 1 - s) << 4) | bidx;
    *(uint4*)&xe [(size_t)m  * NH + c] = u.v;
    *(uint4*)&xer[(size_t)mr * NH + c] = u.v;
    return;
  }
  bx -= 512;
  const float* src = (bx < 16) ? WihF : WihB;
  ushort_t* dst = (bx < 16) ? wihf : wihb;
  int g = ((bx & 15) * 512 + tid) * 8;         // 65536 elems
  float4 a = *(const float4*)(src + g), b = *(const float4*)(src + g + 4);
  union { ushort_t us[8]; uint4 v; } u;
  u.us[0]=f2bf(a.x); u.us[1]=f2bf(a.y); u.us[2]=f2bf(a.z); u.us[3]=f2bf(a.w);
  u.us[4]=f2bf(b.x); u.us[5]=f2bf(b.y); u.us[6]=f2bf(b.z); u.us[7]=f2bf(b.w);
  *(uint4*)&dst[g] = u.v;
}

// batched bf16 transpose: src [z][R][C] -> dst [z][C][R]
__global__ __launch_bounds__(256) void k_transpose(const ushort_t* __restrict__ src,
    ushort_t* __restrict__ dst, int R, int C, long long sstride, long long dstride){
  __shared__ ushort_t tile[32][33];
  int z = blockIdx.z;
  int c0 = blockIdx.x * 32, r0 = blockIdx.y * 32;
  int tx = threadIdx.x & 31, ty = threadIdx.x >> 5;
  const ushort_t* Sp = src + (size_t)sstride * z;
  ushort_t* Dp = dst + (size_t)dstride * z;
  #pragma unroll
  for (int i = 0; i < 32; i += 8) tile[ty+i][tx] = Sp[(size_t)(r0+ty+i) * C + c0 + tx];
  __syncthreads();
  #pragma unroll
  for (int i = 0; i < 32; i += 8) Dp[(size_t)(c0+ty+i) * R + r0 + tx] = tile[tx][ty+i];
}

// ---------------- generic bf16 MFMA GEMM: C[M][N] = A[M][K] * BT[N][K]^T ----------------
// cmode: 0 = fp32 store, 1 = bf16 store, 2 = bf16 store at row (mr*16+z) [ctx remap]
// epilogue guarded by mr < M (allows M=16 with one 128-row m-tile; A must be padded)
__global__ __launch_bounds__(256, 2) void k_gemm(
    const ushort_t* __restrict__ A, const ushort_t* __restrict__ Bt, void* __restrict__ Cp,
    int M, int N, int K, int lda, int ldb, int ldc,
    long long sAz, long long sBz, long long sCz,
    const float* __restrict__ bias,
    const float* __restrict__ rowscale, int rsStride,
    const float* __restrict__ addrow, int ldu,
    float cscale, int cmode){
  __shared__ __align__(16) ushort_t As[128 * 40];
  __shared__ __align__(16) ushort_t Bs[128 * 40];
  int z = blockIdx.z;
  int n0 = blockIdx.x * 128, m0 = blockIdx.y * 128;
  int tid = threadIdx.x;
  int wave = tid >> 6, lane = tid & 63;
  int l15 = lane & 15, q4 = lane >> 4;
  int wm = (wave >> 1) * 64, wn = (wave & 1) * 64;
  const ushort_t* Ab = A + (size_t)sAz * z;
  const ushort_t* Bb = Bt + (size_t)sBz * z;
  // full-tile staging: 128 rows x 32 k-elems = 4096; 256 thr x 16 elems
  int srow = tid >> 1, scol = (tid & 1) * 16;
  f32x4 acc[4][4];
  #pragma unroll
  for (int tm = 0; tm < 4; tm++)
    #pragma unroll
    for (int tn = 0; tn < 4; tn++) acc[tm][tn] = (f32x4){0.f,0.f,0.f,0.f};

  for (int k0 = 0; k0 < K; k0 += 32){
    __syncthreads();
    const ushort_t* ap = Ab + (size_t)(m0+srow)*lda + k0 + scol;
    const ushort_t* bp = Bb + (size_t)(n0+srow)*ldb + k0 + scol;
    *(uint4*)&As[srow*40 + scol]     = *(const uint4*)ap;
    *(uint4*)&As[srow*40 + scol + 8] = *(const uint4*)(ap + 8);
    *(uint4*)&Bs[srow*40 + scol]     = *(const uint4*)bp;
    *(uint4*)&Bs[srow*40 + scol + 8] = *(const uint4*)(bp + 8);
    __syncthreads();
    short8 af[4], bf[4];
    #pragma unroll
    for (int tm = 0; tm < 4; tm++) af[tm] = *(const short8*)&As[(wm + tm*16 + l15)*40 + q4*8];
    #pragma unroll
    for (int tn = 0; tn < 4; tn++) bf[tn] = *(const short8*)&Bs[(wn + tn*16 + l15)*40 + q4*8];
    #pragma unroll
    for (int tm = 0; tm < 4; tm++)
      #pragma unroll
      for (int tn = 0; tn < 4; tn++)
        acc[tm][tn] = __builtin_amdgcn_mfma_f32_16x16x32_bf16(af[tm], bf[tn], acc[tm][tn], 0, 0, 0);
  }

  #pragma unroll
  for (int tm = 0; tm < 4; tm++)
    #pragma unroll
    for (int tn = 0; tn < 4; tn++)
      #pragma unroll
      for (int r = 0; r < 4; r++){
        int mr = m0 + wm + tm*16 + q4*4 + r;
        int nc = n0 + wn + tn*16 + l15;
        if (nc < N && mr < M){
          float v = acc[tm][tn][r] * cscale;
          if (bias)     v += bias[nc];
          if (rowscale) v *= rowscale[(size_t)z * rsStride + mr];
          if (addrow)   v += addrow[(size_t)(mr & 15) * ldu + nc];
          if (cmode == 0){
            ((float*)Cp)[(size_t)sCz * z + (size_t)mr * ldc + nc] = v;
          } else if (cmode == 1){
            ((ushort_t*)Cp)[(size_t)sCz * z + (size_t)mr * ldc + nc] = f2bf(v);
          } else {
            ((ushort_t*)Cp)[((size_t)mr * 16 + z) * ldc + nc] = f2bf(v);
          }
        }
      }
}

// ---------------- fused: sequential RNN (4 blocks) + independent prep (rest) ----------------
// bx 0..3              : RNN, dir = bx>>1, half = bx&1 (8 batches each), prio 1
// next 632 blocks      : fcW cols 0:256 -> fcw1, cols 512:768 -> fcw2 (bf16, zero-pad)
// next 8192 blocks     : pairwise decay w + rsum (one (b,i) row per block)
// next 8 blocks        : p_u gather -> pu bf16 [128][256] (rows >=16 zero)
__global__ __launch_bounds__(512, 1) void k_fused(
    const float* __restrict__ WhhF, const float* __restrict__ WhhB,
    const float* __restrict__ xWf, const float* __restrict__ xWb,
    const float* __restrict__ h0,
    ushort_t* __restrict__ outf,     // [16][512][256] bf16 (fwd dir only)
    float* __restrict__ hout,        // [2][16][256] fp32
    const float* __restrict__ fcW, ushort_t* __restrict__ fcw1, ushort_t* __restrict__ fcw2,
    const float* __restrict__ t, const float* __restrict__ s2,
    ushort_t* __restrict__ wb, float* __restrict__ rsum,
    const int* __restrict__ au, const float* __restrict__ uemb, ushort_t* __restrict__ pu){
  __shared__ __align__(16) ushort_t hl[2][8 * 264];
  int bx = blockIdx.x, tid = threadIdx.x;

  if (bx >= 4){
    int pb = bx - 4;
    if (pb < 632){
      // fcW -> fcw1 (cols 0:256) + fcw2 (cols 512:768)
      int g = pb * 512 + tid;                // 10112*32
      int v = g >> 5, c = (g & 31) << 3;
      union { ushort_t us[8]; uint4 q; } u1, u2;
      if (v < NV){
        const float* p1 = fcW + (size_t)v * 768 + c;
        const float* p2 = p1 + 512;
        float4 a1 = *(const float4*)p1, b1 = *(const float4*)(p1 + 4);
        float4 a2 = *(const float4*)p2, b2 = *(const float4*)(p2 + 4);
        u1.us[0]=f2bf(a1.x); u1.us[1]=f2bf(a1.y); u1.us[2]=f2bf(a1.z); u1.us[3]=f2bf(a1.w);
        u1.us[4]=f2bf(b1.x); u1.us[5]=f2bf(b1.y); u1.us[6]=f2bf(b1.z); u1.us[7]=f2bf(b1.w);
        u2.us[0]=f2bf(a2.x); u2.us[1]=f2bf(a2.y); u2.us[2]=f2bf(a2.z); u2.us[3]=f2bf(a2.w);
        u2.us[4]=f2bf(b2.x); u2.us[5]=f2bf(b2.y); u2.us[6]=f2bf(b2.z); u2.us[7]=f2bf(b2.w);
      } else {
        u1.q = make_uint4(0,0,0,0); u2.q = u1.q;
      }
      *(uint4*)&fcw1[(size_t)v * NH + c] = u1.q;
      *(uint4*)&fcw2[(size_t)v * NH + c] = u2.q;
      return;
    }
    pb -= 632;
    if (pb < 8192){
      // pairwise decay weights, one (b,i) row per block; j = tid
      float* red = (float*)hl;
      int i = pb >> 4, b = pb & 15, j = tid;
      const float C1 = 7.272205216643040e-05f;   // 2*pi/86400
      const float C2 = -1.1574074074074074e-06f; // -0.1/86400
      float ti  = t[i*16 + b];
      float sxi = s2[(size_t)(i*16 + b) * 2], syi = s2[(size_t)(i*16 + b) * 2 + 1];
      float w = 0.f;
      if (j <= i){
        float dt = ti - t[j*16 + b];
        float dx = sxi - s2[(size_t)(j*16 + b) * 2];
        float dy = syi - s2[(size_t)(j*16 + b) * 2 + 1];
        float ds = sqrtf(dx*dx + dy*dy);
        float a = (__cosf(dt * C1) + 1.f) * 0.5f * __expf(dt * C2);
        float bw = __expf(-100.f * ds);
        w = a * bw + 1e-10f;
      }
      wb[((size_t)b * S_LEN + i) * S_LEN + j] = f2bf(w);
      red[j] = w; __syncthreads();
      for (int st = 256; st > 0; st >>= 1){
        if (j < st) red[j] += red[j + st];
        __syncthreads();
      }
      if (j == 0) rsum[b * S_LEN + i] = 1.f / red[0];
      return;
    }
    pb -= 8192;
    // p_u gather -> pu [128][256] bf16, rows >= 16 zero
    int g = pb * 512 + tid;                  // 128*32 = 4096
    int r = g >> 5, c = (g & 31) << 3;
    union { ushort_t us[8]; uint4 q; } u;
    if (r < 16){
      const float* p = uemb + (size_t)au[r] * NH + c;
      float4 a = *(const float4*)p, b2 = *(const float4*)(p + 4);
      u.us[0]=f2bf(a.x); u.us[1]=f2bf(a.y); u.us[2]=f2bf(a.z); u.us[3]=f2bf(a.w);
      u.us[4]=f2bf(b2.x); u.us[5]=f2bf(b2.y); u.us[6]=f2bf(b2.z); u.us[7]=f2bf(b2.w);
    } else {
      u.q = make_uint4(0,0,0,0);
    }
    *(uint4*)&pu[(size_t)r * NH + c] = u.q;
    return;
  }

  // -------- RNN path --------
  int dir = bx >> 1, half = bx & 1;
  const float* Whh = dir ? WhhB : WhhF;
  const float* xW  = dir ? xWb : xWf;
  int wave = tid >> 6, lane = tid & 63;
  int l15 = lane & 15, q4 = lane >> 4;

  for (int idx = tid; idx < 2048; idx += 512){
    int m = idx >> 8, n = idx & 255;
    hl[0][m*264 + n] = f2bf(h0[((size_t)dir * 16 + half * 8 + m) * NH + n]);
  }

  short8 bfr[2][8];   // Whh^T B-fragments, resident (wave's 32-col slice)
  #pragma unroll
  for (int tn = 0; tn < 2; tn++)
    #pragma unroll
    for (int kk = 0; kk < 8; kk++){
      int n = wave*32 + tn*16 + l15;
      int k = kk*32 + q4*8;
      const float* wp = Whh + (size_t)n * NH + k;
      float4 wa = *(const float4*)wp, wb2 = *(const float4*)(wp + 4);
      short8 f;
      f[0]=(short)f2bf(wa.x); f[1]=(short)f2bf(wa.y); f[2]=(short)f2bf(wa.z); f[3]=(short)f2bf(wa.w);
      f[4]=(short)f2bf(wb2.x); f[5]=(short)f2bf(wb2.y); f[6]=(short)f2bf(wb2.z); f[7]=(short)f2bf(wb2.w);
      bfr[tn][kk] = f;
    }

  // per-lane epilogue assignment: 4 values = rows mb..mb+3 of col ncol
  int myTn = q4 >> 1;                          // acc tile: 0 or 1
  int mb   = (q4 & 1) * 4;                     // batch row base (acc rows duplicated)
  int ncol = wave*32 + myTn*16 + l15;

  // xW prefetch, distance 2: even steps use xwE, odd use xwO; one bumped pointer
  const float* xwp = xW + (size_t)(half*8 + mb) * NH + ncol;
  float xwE[4], xwO[4];
  #pragma unroll
  for (int r = 0; r < 4; r++){
    xwE[r] = xwp[r * 256];                 // step 0
    xwO[r] = xwp[r * 256 + 16 * 256];      // step 1
  }
  xwp += 2 * 16 * 256;                     // -> step 2

  // outf store pointers (dir 0 only), bumped by 256 elems (one step) each step
  ushort_t* outp0 = outf + (size_t)(half*8 + mb) * 512 * NH + ncol;
  ushort_t* outp1 = outp0 + (size_t)512 * NH;
  ushort_t* outp2 = outp1 + (size_t)512 * NH;
  ushort_t* outp3 = outp2 + (size_t)512 * NH;

  __builtin_amdgcn_s_setprio(1);   // favor RNN waves over co-resident prep waves
  __syncthreads();   // h0 + bfr staging complete (full drain once is fine)

#define RNN_STEP(S_, RB_, WB_, XWU_)                                              \
  {                                                                               \
    short8 af[8];                                                                 \
    _Pragma("unroll")                                                             \
    for (int kk = 0; kk < 8; kk++)                                                \
      af[kk] = *(const short8*)&hl[RB_][(lane & 7)*264 + kk*32 + q4*8];           \
    f32x4 a0a = (f32x4){0.f,0.f,0.f,0.f}, a0b = a0a, a1a = a0a, a1b = a0a;        \
    _Pragma("unroll")                                                             \
    for (int kk = 0; kk < 4; kk++){                                               \
      a0a = __builtin_amdgcn_mfma_f32_16x16x32_bf16(af[kk], bfr[0][kk], a0a, 0,0,0); \
      a1a = __builtin_amdgcn_mfma_f32_16x16x32_bf16(af[kk], bfr[1][kk], a1a, 0,0,0); \
    }                                                                             \
    _Pragma("unroll")                                                             \
    for (int kk = 4; kk < 8; kk++){                                               \
      a0b = __builtin_amdgcn_mfma_f32_16x16x32_bf16(af[kk], bfr[0][kk], a0b, 0,0,0); \
      a1b = __builtin_amdgcn_mfma_f32_16x16x32_bf16(af[kk], bfr[1][kk], a1b, 0,0,0); \
    }                                                                             \
    f32x4 accS = myTn ? (a1a + a1b) : (a0a + a0b);                                \
    float hv[4];                                                                  \
    _Pragma("unroll")                                                             \
    for (int r = 0; r < 4; r++){                                                  \
      float pre = accS[r] + XWU_[r];                                              \
      float ex = __expf(2.f * pre);                                               \
      hv[r] = 1.f - 2.f * __builtin_amdgcn_rcpf(ex + 1.f);                        \
      hl[WB_][(mb + r)*264 + ncol] = f2bf(hv[r]);                                 \
    }                                                                             \
    if (dir == 0){                                                                \
      outp0[0] = f2bf(hv[0]); outp1[0] = f2bf(hv[1]);                             \
      outp2[0] = f2bf(hv[2]); outp3[0] = f2bf(hv[3]);                             \
      outp0 += 256; outp1 += 256; outp2 += 256; outp3 += 256;                     \
    }                                                                             \
    if ((S_) == 511){                                                             \
      _Pragma("unroll")                                                           \
      for (int r = 0; r < 4; r++)                                                 \
        hout[((size_t)dir*16 + half*8 + mb + r) * NH + ncol] = hv[r];             \
    }                                                                             \
    if ((S_) < 510){                                                              \
      _Pragma("unroll")                                                           \
      for (int r = 0; r < 4; r++) XWU_[r] = xwp[r * 256];                         \
      xwp += 16 * 256;                                                            \
    }                                                                             \
    asm volatile("s_waitcnt lgkmcnt(0)" ::: "memory");                            \
    __builtin_amdgcn_s_barrier();                                                 \
    asm volatile("" ::: "memory");                                                \
  }

  for (int s = 0; s < 512; s += 2){
    RNN_STEP(s,     0, 1, xwE)
    RNN_STEP(s + 1, 1, 0, xwO)
  }
#undef RNN_STEP
}

// ---------------- row softmax: fp32 scores [z][512][512] -> bf16 alpha ----------------
__global__ __launch_bounds__(256) void k_softmax(const float* __restrict__ sc,
                                                 ushort_t* __restrict__ alpha){
  int q = blockIdx.x, z = blockIdx.y, tid = threadIdx.x;
  const float* row = sc + ((size_t)z * S_LEN + q) * S_LEN;
  float v0 = row[tid], v1 = row[tid + 256];
  __shared__ float red[256];
  red[tid] = fmaxf(v0, v1); __syncthreads();
  for (int st = 128; st > 0; st >>= 1){
    if (tid < st) red[tid] = fmaxf(red[tid], red[tid + st]);
    __syncthreads();
  }
  float mx = red[0]; __syncthreads();
  float e0 = __expf(v0 - mx), e1 = __expf(v1 - mx);
  red[tid] = e0 + e1; __syncthreads();
  for (int st = 128; st > 0; st >>= 1){
    if (tid < st) red[tid] += red[tid + st];
    __syncthreads();
  }
  float inv = 1.f / red[0];
  ushort_t* arow = alpha + ((size_t)z * S_LEN + q) * S_LEN;
  arow[tid]       = f2bf(e0 * inv);
  arow[tid + 256] = f2bf(e1 * inv);
}

// ---------------- launch ----------------
extern "C" void kernel_launch(void* const* d_in, const int* in_sizes, int n_in,
                              void* d_out, int out_size, void* d_ws, size_t ws_size,
                              hipStream_t stream){
  const int*   x    = (const int*)d_in[0];
  const float* t    = (const float*)d_in[1];
  const float* s2   = (const float*)d_in[2];
  const float* h0   = (const float*)d_in[5];
  const int*   au   = (const int*)d_in[6];
  const float* emb  = (const float*)d_in[7];
  const float* uemb = (const float*)d_in[8];
  const float* WihF = (const float*)d_in[9];
  const float* WhhF = (const float*)d_in[10];
  const float* bF   = (const float*)d_in[11];
  const float* WihB = (const float*)d_in[12];
  const float* WhhB = (const float*)d_in[13];
  const float* bB   = (const float*)d_in[14];
  const float* fcW  = (const float*)d_in[15];
  const float* fcb  = (const float*)d_in[16];
  float* y    = (float*)d_out;
  float* hout = y + (size_t)S_LEN * NB * NV;

  char* wsc = (char*)d_ws;
  size_t off = 0;
  auto alloc = [&](size_t bytes) -> void* {
    void* p = wsc + off;
    off += (bytes + 255) & ~(size_t)255;
    return p;
  };
  ushort_t* xe    = (ushort_t*)alloc(8192 * 256 * 2);
  ushort_t* xer   = (ushort_t*)alloc(8192 * 256 * 2);
  ushort_t* wihf  = (ushort_t*)alloc(256 * 256 * 2);
  ushort_t* wihb  = (ushort_t*)alloc(256 * 256 * 2);
  float*    xwf   = (float*)alloc((size_t)8192 * 256 * 4);   // reused as scores (with xwb)
  float*    xwb   = (float*)alloc((size_t)8192 * 256 * 4);
  ushort_t* outf  = (ushort_t*)alloc((size_t)16 * 512 * 256 * 2);
  ushort_t* outfT = (ushort_t*)alloc((size_t)16 * 256 * 512 * 2);
  ushort_t* wbuf  = (ushort_t*)alloc((size_t)16 * 512 * 512 * 2);  // reused as alpha
  float*    rsum  = (float*)alloc(16 * 512 * 4);
  ushort_t* owf   = (ushort_t*)alloc((size_t)16 * 512 * 256 * 2);
  ushort_t* owfT  = (ushort_t*)alloc((size_t)16 * 256 * 512 * 2);
  ushort_t* fcw1  = (ushort_t*)alloc((size_t)10112 * 256 * 2);
  float*    ulog  = (float*)alloc((size_t)16 * NV * 4);
  ushort_t* ctx   = (ushort_t*)alloc((size_t)8192 * 256 * 2);
  float*    scores = xwf;          // 16.78 MB, xW dead after k_fused (xwf+xwb contiguous)
  ushort_t* alpha  = wbuf;         // w dead after stage C
  // overlays: xe/xer dead after the two xW GEMMs -> fcw2 (5.18 MB <= 8.39 MB)
  //           wihf+wihb dead after xW GEMMs     -> pu   (64 KB <= 256 KB)
  ushort_t* fcw2 = xe;
  ushort_t* pu   = wihf;

  // prep 0: x_emb gather + Wih cvts
  k_prep0<<<dim3(544), dim3(512), 0, stream>>>(x, emb, xe, xer, WihF, wihf, WihB, wihb);

  // xW = x_emb @ Wih^T + b   (fwd and reversed)
  k_gemm<<<dim3(2, 64, 1), dim3(256), 0, stream>>>(xe, wihf, xwf,
      8192, 256, 256, 256, 256, 256, 0, 0, 0, bF, nullptr, 0, nullptr, 0, 1.f, 0);
  k_gemm<<<dim3(2, 64, 1), dim3(256), 0, stream>>>(xer, wihb, xwb,
      8192, 256, 256, 256, 256, 256, 0, 0, 0, bB, nullptr, 0, nullptr, 0, 1.f, 0);

  // fused: sequential RNNs (4 blocks) + fcw1/fcw2 + pairwise-w + p_u prep (8832 blocks)
  k_fused<<<dim3(4 + 632 + 8192 + 8), dim3(512), 0, stream>>>(
      WhhF, WhhB, xwf, xwb, h0, outf, hout,
      fcW, fcw1, fcw2, t, s2, wbuf, rsum, au, uemb, pu);

  // ulog[b][v] = p_u[b] . fc_W[v][512:768] + fc_b[v]  (MFMA, M=16 via guard)
  k_gemm<<<dim3(79, 1, 1), dim3(256), 0, stream>>>(pu, fcw2, ulog,
      16, NV, 256, 256, 256, NV, 0, 0, 0, fcb, nullptr, 0, nullptr, 0, 1.f, 0);

  // out_f [b][s][h] -> [b][h][s]
  k_transpose<<<dim3(8, 16, 16), dim3(256), 0, stream>>>(outf, outfT, 512, 256,
      (long long)512 * 256, (long long)256 * 512);

  // stage C: out_w = (w @ out_f) / sum_w   -> bf16 [b][512][256]
  k_gemm<<<dim3(2, 4, 16), dim3(256), 0, stream>>>(wbuf, outfT, owf,
      512, 256, 512, 512, 512, 256,
      (long long)512 * 512, (long long)256 * 512, (long long)512 * 256,
      nullptr, rsum, 512, nullptr, 0, 1.f, 1);
  k_transpose<<<dim3(8, 16, 16), dim3(256), 0, stream>>>(owf, owfT, 512, 256,
      (long long)512 * 256, (long long)256 * 512);

  // D1: scores = owf @ owf^T / sqrt(512)
  k_gemm<<<dim3(4, 4, 16), dim3(256), 0, stream>>>(owf, owf, scores,
      512, 512, 256, 256, 256, 512,
      (long long)512 * 256, (long long)512 * 256, (long long)512 * 512,
      nullptr, nullptr, 0, nullptr, 0, 0.04419417382415922f, 0);

  k_softmax<<<dim3(512, 16), dim3(256), 0, stream>>>(scores, alpha);

  // D2: ctx = alpha @ owf  -> bf16 remapped to rows (s*16+b)
  k_gemm<<<dim3(2, 4, 16), dim3(256), 0, stream>>>(alpha, owfT, ctx,
      512, 256, 512, 512, 512, 256,
      (long long)512 * 512, (long long)256 * 512, 0,
      nullptr, nullptr, 0, nullptr, 0, 1.f, 2);

  // E: y = ctx @ fcW1^T + ulog (+fc_b folded into ulog)
  k_gemm<<<dim3(79, 64, 1), dim3(256), 0, stream>>>(ctx, fcw1, y,
      8192, 10000, 256, 256, 256, 10000, 0, 0, 0,
      nullptr, nullptr, 0, ulog, 10000, 1.f, 0);
}